// Round 7
// baseline (595.813 us; speedup 1.0000x reference)
//
#include <hip/hip_runtime.h>

typedef unsigned int uint;
typedef unsigned short ushort;

// Problem constants
#define BB 8
#define SS 4096
#define DD 2048
#define HH 1024
#define EE 8
#define CHUNK 128
#define NCHUNK 32
#define TAU 0.7f

// GEMM tile config
#define BM 128
#define BN 256
#define BK 32              // k per LDS buffer (4 groups of 8)
#define KITERS (DD / BK)   // 64
#define NSLICE (HH / BN)   // 4

typedef short bf16x8 __attribute__((ext_vector_type(8)));    // 8 bf16 = 4 VGPRs
typedef float f32x16 __attribute__((ext_vector_type(16)));   // 32x32 C frag

// RTNE f32 pair -> packed bf16x2 (a in low 16, b in high 16)
__device__ inline uint pack_rn(float a, float b) {
    uint ua = __float_as_uint(a), ub = __float_as_uint(b);
    ua += 0x7FFFu + ((ua >> 16) & 1u);
    ub += 0x7FFFu + ((ub >> 16) & 1u);
    return (ua >> 16) | (ub & 0xFFFF0000u);
}

// ---------------------------------------------------------------------------
// Pre-pass: reorder W1 [D][H] fp32 -> single RTNE bf16 in MFMA-B-staged layout
// [D/8][H][8] (k-group major, 8 consecutive k per 16B).
// ---------------------------------------------------------------------------
__global__ __launch_bounds__(256) void reorder_w1_kernel(
    const float* __restrict__ W1, ushort* __restrict__ w1b)
{
    const int kg = blockIdx.x >> 2;                       // 0..255
    const int n  = ((blockIdx.x & 3) << 8) + threadIdx.x; // 0..1023
    float v[8];
#pragma unroll
    for (int j = 0; j < 8; ++j) v[j] = W1[(size_t)(kg * 8 + j) * HH + n];
    uint pk[4];
#pragma unroll
    for (int p = 0; p < 4; ++p) pk[p] = pack_rn(v[2 * p], v[2 * p + 1]);
    const size_t off = (size_t)kg * HH + n;               // uint4 index
    ((uint4*)w1b)[off] = make_uint4(pk[0], pk[1], pk[2], pk[3]);
}

// ---------------------------------------------------------------------------
// Fused router GEMM — counted-vmcnt 2-phase pipeline (T3/T4), raw s_barrier.
// All staging via global_load_lds (A as fp32, packed to bf16 at read time;
// B as pre-packed bf16). Double-buffered LDS; vmcnt never drains to 0 in-loop.
// XCD swizzle: the 4 H-slices of one (batch,chunk) share an XCD's L2.
// ---------------------------------------------------------------------------
__global__ __launch_bounds__(256, 2) void router_gemm_kernel(
    const float* __restrict__ x,
    const ushort* __restrict__ w1b,    // [D/8][H][8] bf16 bits
    const float* __restrict__ b1,
    const float* __restrict__ W2,
    float* __restrict__ chunk_logits)  // [B*NCHUNK][E], pre-zeroed
{
    // XCD-aware decode: bid%8 = XCD; 4 consecutive local ids = 4 slices of one bc
    const int bid   = blockIdx.x;         // 0..1023
    const int xcd   = bid & 7;
    const int loc   = bid >> 3;           // 0..127
    const int bc    = xcd * 32 + (loc >> 2);
    const int slice = loc & 3;
    const int n0    = slice * BN;

    const int tid  = threadIdx.x;      // 0..255
    const int wave = tid >> 6;         // 0..3
    const int lane = tid & 63;
    const int lm   = lane & 31;        // row/col within 32-tile
    const int kq   = lane >> 5;        // k-octet select
    const int wn   = wave * 64;        // wave n offset (1x4 layout, full m)

    // double-buffered tiles
    __shared__ __align__(16) float  As_f[2][4][2][BM][4]; // [buf][kg][half][m][4f] fp32, 32KB
    __shared__ __align__(16) ushort Bs[2][4][BN][8];      // [buf][kg][n][8k] bf16, 32KB
    __shared__ float  W2s[BN][EE];                        // 8KB
    __shared__ float  b1s[BN];                            // 1KB
    __shared__ float  red[4][EE];

    const float* xrow = x + (size_t)bc * CHUNK * DD;

    // Stage W2 slice + b1 slice (visible by first loop-end barrier; read in epilogue)
    ((float4*)&W2s[0][0])[tid]       = ((const float4*)(W2 + (size_t)n0 * EE))[tid];
    ((float4*)&W2s[0][0])[tid + 256] = ((const float4*)(W2 + (size_t)n0 * EE))[tid + 256];
    if (tid < BN / 4) ((float4*)b1s)[tid] = ((const float4*)(b1 + n0))[tid];

    f32x16 acc[4][2];
#pragma unroll
    for (int i = 0; i < 4; ++i)
#pragma unroll
        for (int j = 0; j < 2; ++j)
#pragma unroll
            for (int r = 0; r < 16; ++r) acc[i][j][r] = 0.0f;

// Issue all staging for k-step (tp) into buffer (buf): 8 glds/wave
// (4 x A-fp32 + 4 x B-bf16), zero VALU, wave-uniform LDS base + lane*16.
#define STAGE(tp, buf) do {                                                          \
        _Pragma("unroll")                                                            \
        for (int i = 0; i < 4; ++i) {                                               \
            const int half_ = i >> 1;                                                \
            const int mrow_ = (i & 1) * 64 + lane;                                   \
            const float* gsrc_ = xrow + (size_t)mrow_ * DD                           \
                                 + ((tp) * BK + wave * 8 + half_ * 4);               \
            __builtin_amdgcn_global_load_lds(                                        \
                (const __attribute__((address_space(1))) uint*)gsrc_,                \
                (__attribute__((address_space(3))) uint*)&As_f[buf][wave][half_][mrow_][0], \
                16, 0, 0);                                                           \
        }                                                                            \
        {                                                                            \
            const int kgg_ = (tp) * 4 + wave;                                        \
            _Pragma("unroll")                                                        \
            for (int h = 0; h < 4; ++h) {                                            \
                const size_t goff_ = ((size_t)kgg_ * HH + n0 + h * 64 + lane) * 8;   \
                __builtin_amdgcn_global_load_lds(                                    \
                    (const __attribute__((address_space(1))) uint*)(w1b + goff_),    \
                    (__attribute__((address_space(3))) uint*)&Bs[buf][wave][h * 64 + lane][0], \
                    16, 0, 0);                                                       \
            }                                                                        \
        }                                                                            \
    } while (0)

// Compute on buffer (buf): ds_read A-fp32 + pack + ds_read B + 16 MFMA.
#define MFMA_PHASE(buf) do {                                                         \
        _Pragma("unroll")                                                            \
        for (int s = 0; s < 2; ++s) {                                                \
            const int kg = 2 * s + kq;                                               \
            bf16x8 a[4], b[2];                                                       \
            _Pragma("unroll")                                                        \
            for (int i = 0; i < 4; ++i) {                                            \
                const float4 lo = *(const float4*)&As_f[buf][kg][0][i * 32 + lm][0]; \
                const float4 hi = *(const float4*)&As_f[buf][kg][1][i * 32 + lm][0]; \
                uint4 pk4 = make_uint4(pack_rn(lo.x, lo.y), pack_rn(lo.z, lo.w),     \
                                       pack_rn(hi.x, hi.y), pack_rn(hi.z, hi.w));    \
                a[i] = *(bf16x8*)&pk4;                                               \
            }                                                                        \
            _Pragma("unroll")                                                        \
            for (int j = 0; j < 2; ++j)                                              \
                b[j] = *(const bf16x8*)&Bs[buf][kg][wn + j * 32 + lm][0];            \
            __builtin_amdgcn_s_setprio(1);                                           \
            _Pragma("unroll")                                                        \
            for (int i = 0; i < 4; ++i)                                              \
                _Pragma("unroll")                                                    \
                for (int j = 0; j < 2; ++j)                                          \
                    acc[i][j] = __builtin_amdgcn_mfma_f32_32x32x16_bf16(             \
                        a[i], b[j], acc[i][j], 0, 0, 0);                             \
            __builtin_amdgcn_s_setprio(0);                                           \
        }                                                                            \
    } while (0)

    // ---- prologue: stage k-step 0 into buffer 0, drain once ----
    STAGE(0, 0);
    asm volatile("s_waitcnt vmcnt(0)" ::: "memory");
    __builtin_amdgcn_s_barrier();
    asm volatile("" ::: "memory");

    // ---- main loop: counted vmcnt, loads for t+1 stay in flight across compute ----
    for (int t = 0; t < KITERS - 1; ++t) {
        const int cur = t & 1;
        STAGE(t + 1, cur ^ 1);                         // 8 glds -> outstanding 16
        asm volatile("s_waitcnt vmcnt(8)" ::: "memory"); // my t-loads (oldest 8) done
        __builtin_amdgcn_s_barrier();                  // all waves' t-loads done
        asm volatile("" ::: "memory");
        MFMA_PHASE(cur);
        asm volatile("s_waitcnt lgkmcnt(0)" ::: "memory"); // my reads of buf[cur] done
        __builtin_amdgcn_s_barrier();                  // all waves done reading buf[cur]
        asm volatile("" ::: "memory");
    }
    // tail: drain and compute last k-step
    asm volatile("s_waitcnt vmcnt(0)" ::: "memory");
    __builtin_amdgcn_s_barrier();
    asm volatile("" ::: "memory");
    MFMA_PHASE((KITERS - 1) & 1);

    // ---- Epilogue: relu + second GEMM + chunk partial sum ----
    float part[EE];
#pragma unroll
    for (int e = 0; e < EE; ++e) part[e] = 0.0f;

#pragma unroll
    for (int j = 0; j < 2; ++j) {
        const int hl = wn + j * 32 + lm;       // local h (col of C)
        const float bias = b1s[hl];
        float w2r[EE];
#pragma unroll
        for (int e = 0; e < EE; ++e) w2r[e] = W2s[hl][e];
#pragma unroll
        for (int i = 0; i < 4; ++i)
#pragma unroll
            for (int r = 0; r < 16; ++r) {
                const float hv = fmaxf(acc[i][j][r] + bias, 0.0f);
#pragma unroll
                for (int e = 0; e < EE; ++e) part[e] = fmaf(hv, w2r[e], part[e]);
            }
    }

#pragma unroll
    for (int off = 32; off >= 1; off >>= 1)
#pragma unroll
        for (int e = 0; e < EE; ++e) part[e] += __shfl_down(part[e], off, 64);

    if (lane == 0)
#pragma unroll
        for (int e = 0; e < EE; ++e) red[wave][e] = part[e];
    __syncthreads();
    if (tid < EE) {
        const float s = red[0][tid] + red[1][tid] + red[2][tid] + red[3][tid];
        atomicAdd(&chunk_logits[(size_t)bc * EE + tid], s * (1.0f / CHUNK));
    }
}

// ---------------------------------------------------------------------------
// Fused finalize: add b2, per-batch hysteresis scan (redundant per block,
// tiny), one-hot writes + expert-index writes. One block = 256 tokens.
// ---------------------------------------------------------------------------
__global__ __launch_bounds__(256) void finalize_kernel(
    const float* __restrict__ chunk_logits,  // [B*NCHUNK][E]
    const float* __restrict__ b2,
    float* __restrict__ out)
{
    __shared__ float cls[NCHUNK][EE];
    __shared__ int   idxs[NCHUNK];
    const int tid = threadIdx.x;              // 0..255
    const int b   = blockIdx.x >> 4;          // 0..7
    const int sg  = blockIdx.x & 15;          // 0..15 (256-token group)

    // load this batch's chunk logits + b2 (one thread per (c,e); 32*8 == 256)
    {
        const int c = tid >> 3, e = tid & 7;
        cls[c][e] = chunk_logits[(size_t)(b * NCHUNK + c) * EE + e] + b2[e];
    }
    __syncthreads();

    // serial hysteresis scan (tiny: 32 chunks x 8 experts from LDS)
    if (tid == 0) {
        int prev = 0;
        for (int c = 0; c < NCHUNK; ++c) {
            float best = -3.4e38f;
            int ce = 0;
#pragma unroll
            for (int e = 0; e < EE; ++e) {
                const float lv = cls[c][e];
                if (lv > best) { best = lv; ce = e; }
            }
            if (c == 0) prev = ce;
            else if (best - cls[c][prev] > TAU) prev = ce;
            idxs[c] = prev;
        }
    }
    __syncthreads();

    // one-hot routing weights: 1 token/thread, two float4 stores
    const int tok = sg * 256 + tid;           // 0..4095
    const int id  = idxs[tok >> 7];
    float v[EE];
#pragma unroll
    for (int e = 0; e < EE; ++e) v[e] = (e == id) ? 1.0f : 0.0f;
    float4* o = (float4*)(out + ((size_t)b * SS + tok) * EE);
    o[0] = make_float4(v[0], v[1], v[2], v[3]);
    o[1] = make_float4(v[4], v[5], v[6], v[7]);

    // expert index tail (once per batch)
    if (sg == 0 && tid < NCHUNK)
        out[(size_t)BB * SS * EE + b * NCHUNK + tid] = (float)idxs[tid];
}

// ---------------------------------------------------------------------------
extern "C" void kernel_launch(void* const* d_in, const int* in_sizes, int n_in,
                              void* d_out, int out_size, void* d_ws, size_t ws_size,
                              hipStream_t stream)
{
    const float* x  = (const float*)d_in[0];
    const float* W1 = (const float*)d_in[1];
    const float* b1 = (const float*)d_in[2];
    const float* W2 = (const float*)d_in[3];
    const float* b2 = (const float*)d_in[4];
    float* out = (float*)d_out;

    // ws layout: W1b (4MB) | pad | chunk_logits (8KB)
    ushort* w1b          = (ushort*)d_ws;
    float*  chunk_logits = (float*)((char*)d_ws + (size_t)8 * 1024 * 1024);

    hipMemsetAsync(chunk_logits, 0, BB * NCHUNK * EE * sizeof(float), stream);

    reorder_w1_kernel<<<1024, 256, 0, stream>>>(W1, w1b);

    router_gemm_kernel<<<NSLICE * BB * NCHUNK, 256, 0, stream>>>(
        x, w1b, b1, W2, chunk_logits);

    finalize_kernel<<<BB * 16, 256, 0, stream>>>(chunk_logits, b2, out);
}

// Round 8
// 579.769 us; speedup vs baseline: 1.0277x; 1.0277x over previous
//
#include <hip/hip_runtime.h>

typedef unsigned int uint;
typedef unsigned short ushort;

// Problem constants
#define BB 8
#define SS 4096
#define DD 2048
#define HH 1024
#define EE 8
#define CHUNK 128
#define NCHUNK 32
#define TAU 0.7f

// GEMM tile config
#define BM 128
#define BN 256
#define BK 32              // k per LDS buffer (4 groups of 8)
#define KITERS (DD / BK)   // 64
#define NSLICE (HH / BN)   // 4

typedef short bf16x8 __attribute__((ext_vector_type(8)));    // 8 bf16 = 4 VGPRs
typedef float f32x16 __attribute__((ext_vector_type(16)));   // 32x32 C frag

// RTNE f32 pair -> packed bf16x2 (a in low 16, b in high 16)
__device__ inline uint pack_rn(float a, float b) {
    uint ua = __float_as_uint(a), ub = __float_as_uint(b);
    ua += 0x7FFFu + ((ua >> 16) & 1u);
    ub += 0x7FFFu + ((ub >> 16) & 1u);
    return (ua >> 16) | (ub & 0xFFFF0000u);
}

// ---------------------------------------------------------------------------
// Pre-pass: reorder W1 [D][H] fp32 -> single RTNE bf16 in MFMA-B-staged layout
// [D/8][H][8] (k-group major, 8 consecutive k per 16B).
// ---------------------------------------------------------------------------
__global__ __launch_bounds__(256) void reorder_w1_kernel(
    const float* __restrict__ W1, ushort* __restrict__ w1b)
{
    const int kg = blockIdx.x >> 2;                       // 0..255
    const int n  = ((blockIdx.x & 3) << 8) + threadIdx.x; // 0..1023
    float v[8];
#pragma unroll
    for (int j = 0; j < 8; ++j) v[j] = W1[(size_t)(kg * 8 + j) * HH + n];
    uint pk[4];
#pragma unroll
    for (int p = 0; p < 4; ++p) pk[p] = pack_rn(v[2 * p], v[2 * p + 1]);
    const size_t off = (size_t)kg * HH + n;               // uint4 index
    ((uint4*)w1b)[off] = make_uint4(pk[0], pk[1], pk[2], pk[3]);
}

// ---------------------------------------------------------------------------
// Fused router GEMM — double-buffered prefetch, cheap-drain ordering:
// issue B glds(t+1) + A reg-loads(t+1) BEFORE MFMA(t); pack+ds_write AFTER.
// __syncthreads' vmcnt(0) then waits only on loads issued a full MFMA phase
// earlier (mostly L2 hits via XCD swizzle). A packed ONCE per element.
// ---------------------------------------------------------------------------
__global__ __launch_bounds__(256, 2) void router_gemm_kernel(
    const float* __restrict__ x,
    const ushort* __restrict__ w1b,    // [D/8][H][8] bf16 bits
    const float* __restrict__ b1,
    const float* __restrict__ W2,
    float* __restrict__ chunk_logits)  // [B*NCHUNK][E], pre-zeroed
{
    // XCD-aware decode: bid%8 = XCD; 4 consecutive local ids = 4 slices of one bc
    const int bid   = blockIdx.x;         // 0..1023
    const int xcd   = bid & 7;
    const int loc   = bid >> 3;           // 0..127
    const int bc    = xcd * 32 + (loc >> 2);
    const int slice = loc & 3;
    const int n0    = slice * BN;

    const int tid  = threadIdx.x;      // 0..255
    const int wave = tid >> 6;         // 0..3
    const int lane = tid & 63;
    const int lm   = lane & 31;        // row/col within 32-tile
    const int kq   = lane >> 5;        // k-octet select
    const int wn   = wave * 64;        // wave n offset (1x4 layout, full m)

    // double-buffered tiles: [buf][kg][row][8k]
    __shared__ __align__(16) ushort As[2][4][BM][8];   // 16KB bf16
    __shared__ __align__(16) ushort Bs[2][4][BN][8];   // 32KB bf16
    __shared__ float  W2s[BN][EE];                     // 8KB
    __shared__ float  b1s[BN];                         // 1KB
    __shared__ float  red[4][EE];

    const float* xrow = x + (size_t)bc * CHUNK * DD;

    // Stage W2 slice + b1 slice (read only in epilogue)
    ((float4*)&W2s[0][0])[tid]       = ((const float4*)(W2 + (size_t)n0 * EE))[tid];
    ((float4*)&W2s[0][0])[tid + 256] = ((const float4*)(W2 + (size_t)n0 * EE))[tid + 256];
    if (tid < BN / 4) ((float4*)b1s)[tid] = ((const float4*)(b1 + n0))[tid];

    f32x16 acc[4][2];
#pragma unroll
    for (int i = 0; i < 4; ++i)
#pragma unroll
        for (int j = 0; j < 2; ++j)
#pragma unroll
            for (int r = 0; r < 16; ++r) acc[i][j][r] = 0.0f;

    // A staging coords: thread -> (m, k-half)
    const int am = tid >> 1;          // 0..127
    const int ah = tid & 1;           // 0/1: k0+ah*16 .. +16
    const float* asrc = xrow + (size_t)am * DD + ah * 16;

// Issue B-tile async global->LDS for k-step (tp) into buffer (buf): 4 glds/wave.
#define STAGE_B(tp, buf) do {                                                        \
        const int kgg_ = (tp) * 4 + wave;                                            \
        _Pragma("unroll")                                                            \
        for (int h = 0; h < 4; ++h) {                                                \
            const size_t goff_ = ((size_t)kgg_ * HH + n0 + h * 64 + lane) * 8;       \
            __builtin_amdgcn_global_load_lds(                                        \
                (const __attribute__((address_space(1))) uint*)(w1b + goff_),        \
                (__attribute__((address_space(3))) uint*)&Bs[buf][wave][h * 64 + lane][0], \
                16, 0, 0);                                                           \
        }                                                                            \
    } while (0)

// Convert 16 fp32 in v0..v3 to bf16 (RTNE, once per element) and write LDS.
#define WRITE_A(v0, v1, v2, v3, buf) do {                                            \
        const float f_[16] = {v0.x, v0.y, v0.z, v0.w, v1.x, v1.y, v1.z, v1.w,        \
                              v2.x, v2.y, v2.z, v2.w, v3.x, v3.y, v3.z, v3.w};       \
        uint pk_[8];                                                                 \
        _Pragma("unroll")                                                            \
        for (int p = 0; p < 8; ++p) pk_[p] = pack_rn(f_[2 * p], f_[2 * p + 1]);      \
        const int kg0_ = ah * 2;                                                     \
        *(uint4*)&As[buf][kg0_][am][0]     = make_uint4(pk_[0], pk_[1], pk_[2], pk_[3]); \
        *(uint4*)&As[buf][kg0_ + 1][am][0] = make_uint4(pk_[4], pk_[5], pk_[6], pk_[7]); \
    } while (0)

// Compute on buffer (buf): 12 ds_read_b128 + 16 MFMA per wave.
#define MFMA_PHASE(buf) do {                                                         \
        _Pragma("unroll")                                                            \
        for (int s = 0; s < 2; ++s) {                                                \
            const int kg = 2 * s + kq;                                               \
            bf16x8 a[4], b[2];                                                       \
            _Pragma("unroll")                                                        \
            for (int i = 0; i < 4; ++i)                                              \
                a[i] = *(const bf16x8*)&As[buf][kg][i * 32 + lm][0];                 \
            _Pragma("unroll")                                                        \
            for (int j = 0; j < 2; ++j)                                              \
                b[j] = *(const bf16x8*)&Bs[buf][kg][wn + j * 32 + lm][0];            \
            __builtin_amdgcn_s_setprio(1);                                           \
            _Pragma("unroll")                                                        \
            for (int i = 0; i < 4; ++i)                                              \
                _Pragma("unroll")                                                    \
                for (int j = 0; j < 2; ++j)                                          \
                    acc[i][j] = __builtin_amdgcn_mfma_f32_32x32x16_bf16(             \
                        a[i], b[j], acc[i][j], 0, 0, 0);                             \
            __builtin_amdgcn_s_setprio(0);                                           \
        }                                                                            \
    } while (0)

    // ---- prologue: stage k-step 0 into buffer 0 ----
    {
        float4 v0 = ((const float4*)asrc)[0];
        float4 v1 = ((const float4*)asrc)[1];
        float4 v2 = ((const float4*)asrc)[2];
        float4 v3 = ((const float4*)asrc)[3];
        STAGE_B(0, 0);
        WRITE_A(v0, v1, v2, v3, 0);
    }
    __syncthreads();

    // ---- main loop: issue t+1 loads || compute t || write t+1 ----
    for (int t = 0; t < KITERS - 1; ++t) {
        const int cur = t & 1;
        STAGE_B(t + 1, cur ^ 1);                 // B glds in flight across MFMA
        const float* s2 = asrc + (size_t)(t + 1) * BK;
        float4 v0 = ((const float4*)s2)[0];      // A -> regs, latency hidden
        float4 v1 = ((const float4*)s2)[1];      // under the MFMA phase
        float4 v2 = ((const float4*)s2)[2];
        float4 v3 = ((const float4*)s2)[3];
        MFMA_PHASE(cur);
        WRITE_A(v0, v1, v2, v3, cur ^ 1);        // pack once, ds_write
        __syncthreads();                         // vmcnt(0) cheap: B glds are old
    }
    // last k-step: compute only
    MFMA_PHASE((KITERS - 1) & 1);

    // ---- Epilogue: relu + second GEMM + chunk partial sum ----
    float part[EE];
#pragma unroll
    for (int e = 0; e < EE; ++e) part[e] = 0.0f;

#pragma unroll
    for (int j = 0; j < 2; ++j) {
        const int hl = wn + j * 32 + lm;       // local h (col of C)
        const float bias = b1s[hl];
        float w2r[EE];
#pragma unroll
        for (int e = 0; e < EE; ++e) w2r[e] = W2s[hl][e];
#pragma unroll
        for (int i = 0; i < 4; ++i)
#pragma unroll
            for (int r = 0; r < 16; ++r) {
                const float hv = fmaxf(acc[i][j][r] + bias, 0.0f);
#pragma unroll
                for (int e = 0; e < EE; ++e) part[e] = fmaf(hv, w2r[e], part[e]);
            }
    }

#pragma unroll
    for (int off = 32; off >= 1; off >>= 1)
#pragma unroll
        for (int e = 0; e < EE; ++e) part[e] += __shfl_down(part[e], off, 64);

    if (lane == 0)
#pragma unroll
        for (int e = 0; e < EE; ++e) red[wave][e] = part[e];
    __syncthreads();
    if (tid < EE) {
        const float s = red[0][tid] + red[1][tid] + red[2][tid] + red[3][tid];
        atomicAdd(&chunk_logits[(size_t)bc * EE + tid], s * (1.0f / CHUNK));
    }
}

// ---------------------------------------------------------------------------
// Fused finalize: add b2, per-batch hysteresis scan (redundant per block,
// tiny), one-hot writes + expert-index writes. One block = 256 tokens.
// ---------------------------------------------------------------------------
__global__ __launch_bounds__(256) void finalize_kernel(
    const float* __restrict__ chunk_logits,  // [B*NCHUNK][E]
    const float* __restrict__ b2,
    float* __restrict__ out)
{
    __shared__ float cls[NCHUNK][EE];
    __shared__ int   idxs[NCHUNK];
    const int tid = threadIdx.x;              // 0..255
    const int b   = blockIdx.x >> 4;          // 0..7
    const int sg  = blockIdx.x & 15;          // 0..15 (256-token group)

    // load this batch's chunk logits + b2 (one thread per (c,e); 32*8 == 256)
    {
        const int c = tid >> 3, e = tid & 7;
        cls[c][e] = chunk_logits[(size_t)(b * NCHUNK + c) * EE + e] + b2[e];
    }
    __syncthreads();

    // serial hysteresis scan (tiny: 32 chunks x 8 experts from LDS)
    if (tid == 0) {
        int prev = 0;
        for (int c = 0; c < NCHUNK; ++c) {
            float best = -3.4e38f;
            int ce = 0;
#pragma unroll
            for (int e = 0; e < EE; ++e) {
                const float lv = cls[c][e];
                if (lv > best) { best = lv; ce = e; }
            }
            if (c == 0) prev = ce;
            else if (best - cls[c][prev] > TAU) prev = ce;
            idxs[c] = prev;
        }
    }
    __syncthreads();

    // one-hot routing weights: 1 token/thread, two float4 stores
    const int tok = sg * 256 + tid;           // 0..4095
    const int id  = idxs[tok >> 7];
    float v[EE];
#pragma unroll
    for (int e = 0; e < EE; ++e) v[e] = (e == id) ? 1.0f : 0.0f;
    float4* o = (float4*)(out + ((size_t)b * SS + tok) * EE);
    o[0] = make_float4(v[0], v[1], v[2], v[3]);
    o[1] = make_float4(v[4], v[5], v[6], v[7]);

    // expert index tail (once per batch)
    if (sg == 0 && tid < NCHUNK)
        out[(size_t)BB * SS * EE + b * NCHUNK + tid] = (float)idxs[tid];
}

// ---------------------------------------------------------------------------
extern "C" void kernel_launch(void* const* d_in, const int* in_sizes, int n_in,
                              void* d_out, int out_size, void* d_ws, size_t ws_size,
                              hipStream_t stream)
{
    const float* x  = (const float*)d_in[0];
    const float* W1 = (const float*)d_in[1];
    const float* b1 = (const float*)d_in[2];
    const float* W2 = (const float*)d_in[3];
    const float* b2 = (const float*)d_in[4];
    float* out = (float*)d_out;

    // ws layout: W1b (4MB) | pad | chunk_logits (8KB)
    ushort* w1b          = (ushort*)d_ws;
    float*  chunk_logits = (float*)((char*)d_ws + (size_t)8 * 1024 * 1024);

    hipMemsetAsync(chunk_logits, 0, BB * NCHUNK * EE * sizeof(float), stream);

    reorder_w1_kernel<<<1024, 256, 0, stream>>>(W1, w1b);

    router_gemm_kernel<<<NSLICE * BB * NCHUNK, 256, 0, stream>>>(
        x, w1b, b1, W2, chunk_logits);

    finalize_kernel<<<BB * 16, 256, 0, stream>>>(chunk_logits, b2, out);
}